// Round 1
// baseline (1052.973 us; speedup 1.0000x reference)
//
#include <hip/hip_runtime.h>
#include <hip/hip_bf16.h>
#include <stdint.h>

// Problem constants (fixed benchmark): B=8, S=1024, HID=1024, NH=16, HD=64, MAX_REL=64
#define SEQ 1024
#define NHEAD 16
#define HDIM 64

typedef unsigned short u16;
typedef __attribute__((ext_vector_type(8))) short short8;
typedef __attribute__((ext_vector_type(4))) float f32x4;

static __device__ __forceinline__ u16 f2bf(float f) {
  union { float f; unsigned int u; } v; v.f = f;
  unsigned int u = v.u;
  unsigned int r = u + 0x7fffu + ((u >> 16) & 1u);   // RNE
  return (u16)(r >> 16);
}
static __device__ __forceinline__ float bf2f(u16 h) {
  union { unsigned int u; float f; } v; v.u = ((unsigned int)h) << 16;
  return v.f;
}

// ---------------- f32 -> bf16 convert ----------------
__global__ __launch_bounds__(256) void cvt_f32_bf16(const float* __restrict__ src,
                                                    u16* __restrict__ dst, int n) {
  int i = (blockIdx.x * 256 + threadIdx.x) * 4;
  if (i < n) {
    float4 v = *(const float4*)(src + i);
    ushort4 o;
    o.x = f2bf(v.x); o.y = f2bf(v.y); o.z = f2bf(v.z); o.w = f2bf(v.w);
    *(ushort4*)(dst + i) = o;
  }
}

// ---------------- GEMM: C[m][n] = sum_k A[m][k]*Bw[n][k] + bias[n] ----------------
// A [M][K] bf16 row-major, Bw [N][K] bf16 row-major (i.e. computes A @ Bw^T).
// 128x128 tile, BK=32, 256 threads (4 waves, each a 64x64 quadrant).
template<int OUTF32>
__global__ __launch_bounds__(256) void gemm_bt(const u16* __restrict__ A,
                                               const u16* __restrict__ Bw,
                                               const float* __restrict__ bias,
                                               void* __restrict__ Cout,
                                               int M, int N, int K) {
  const int tid  = threadIdx.x;
  const int lane = tid & 63;
  const int w    = tid >> 6;
  const int g    = lane >> 4;
  const int li   = lane & 15;
  const int m0 = blockIdx.y * 128;
  const int n0 = blockIdx.x * 128;
  const int wm = (w >> 1) * 64;
  const int wn = (w & 1) * 64;

  __shared__ alignas(16) u16 As[2][128][40];  // +8 pad: 80B row stride -> conflict-free-ish
  __shared__ alignas(16) u16 Bs[2][128][40];

  f32x4 acc[4][4];
#pragma unroll
  for (int mt = 0; mt < 4; ++mt)
#pragma unroll
    for (int nt = 0; nt < 4; ++nt) acc[mt][nt] = (f32x4){0.f, 0.f, 0.f, 0.f};

  uint4 ra[2], rb[2];
  const int KT = K >> 5;

  // load tile kt into regs
  auto loadt = [&](int kt) {
    int k0 = kt * 32;
#pragma unroll
    for (int c = 0; c < 2; ++c) {
      int flat = c * 256 + tid;
      int row = flat >> 2;
      int col = (flat & 3) * 8;
      ra[c] = *(const uint4*)(A  + (size_t)(m0 + row) * K + k0 + col);
      rb[c] = *(const uint4*)(Bw + (size_t)(n0 + row) * K + k0 + col);
    }
  };
  auto storet = [&](int b) {
#pragma unroll
    for (int c = 0; c < 2; ++c) {
      int flat = c * 256 + tid;
      int row = flat >> 2;
      int col = (flat & 3) * 8;
      *(uint4*)(&As[b][row][col]) = ra[c];
      *(uint4*)(&Bs[b][row][col]) = rb[c];
    }
  };

  loadt(0); storet(0);
  for (int t = 0; t < KT; ++t) {
    __syncthreads();
    if (t + 1 < KT) loadt(t + 1);     // issue next-tile global loads early
    int b = t & 1;
    short8 af[4], bfr[4];
#pragma unroll
    for (int mt = 0; mt < 4; ++mt)
      af[mt] = *(const short8*)(&As[b][wm + mt * 16 + li][g * 8]);
#pragma unroll
    for (int nt = 0; nt < 4; ++nt)
      bfr[nt] = *(const short8*)(&Bs[b][wn + nt * 16 + li][g * 8]);
#pragma unroll
    for (int mt = 0; mt < 4; ++mt)
#pragma unroll
      for (int nt = 0; nt < 4; ++nt)
        acc[mt][nt] = __builtin_amdgcn_mfma_f32_16x16x32_bf16(af[mt], bfr[nt], acc[mt][nt], 0, 0, 0);
    if (t + 1 < KT) storet((t + 1) & 1);  // write other buffer after compute
  }

#pragma unroll
  for (int mt = 0; mt < 4; ++mt) {
#pragma unroll
    for (int nt = 0; nt < 4; ++nt) {
      int col = n0 + wn + nt * 16 + li;
      float bv = bias[col];
#pragma unroll
      for (int r = 0; r < 4; ++r) {
        int row = m0 + wm + mt * 16 + g * 4 + r;
        float v = acc[mt][nt][r] + bv;
        if (OUTF32) ((float*)Cout)[(size_t)row * N + col] = v;
        else        ((u16*)Cout)[(size_t)row * N + col]   = f2bf(v);
      }
    }
  }
}

// ---------------- Fused attention with rank-129 relative embedding ----------------
// rel[i,j,:] = table[clip(j-i,-64,64)+64,:]; table extracted from rel row i=512.
// Per block: one (b,h) pair, 64 q-rows. 256 threads = 4 waves, wave owns 16 rows.
__global__ __launch_bounds__(256) void attn_kernel(const u16* __restrict__ Qb,
                                                   const u16* __restrict__ Kb,
                                                   const u16* __restrict__ Vb,
                                                   const float* __restrict__ rel,
                                                   u16* __restrict__ Cb) {
  const int tid  = threadIdx.x;
  const int lane = tid & 63;
  const int w    = tid >> 6;
  const int g    = lane >> 4;
  const int li   = lane & 15;

  const int bh = blockIdx.x >> 4;   // 0..127 (b*16+h)
  const int it = blockIdx.x & 15;
  const int b  = bh >> 4;
  const int h  = bh & 15;
  const int i0 = it * 64;

  __shared__ alignas(16) u16 Qs[64][72];
  union U {
    struct { u16 Ks[128][72]; u16 Vt[64][136]; u16 Ps[64][136]; } a;   // main loop
    struct { u16 Bb[64][168]; u16 Tt[64][168]; } e;                    // epilogue
  };
  __shared__ alignas(16) U u;
  __shared__ alignas(16) u16  Tb[144][72];   // table[d][h], rows 129..143 zero
  __shared__ alignas(16) u16  Qr[64][132];   // qrel[i][d] bf16
  __shared__ alignas(16) float Bd[64][132];  // band[i][d] f32

  // ---- stage Q tile ----
  const size_t qbase = ((size_t)(b * SEQ + i0)) * 1024 + h * HDIM;
#pragma unroll
  for (int c = 0; c < 2; ++c) {
    int flat = c * 256 + tid;
    int row = flat >> 3, col = (flat & 7) * 8;
    *(uint4*)(&Qs[row][col]) = *(const uint4*)(Qb + qbase + (size_t)row * 1024 + col);
  }
  // ---- extract table from rel row i=512: table[d][h] = rel[512][448+d][h] ----
  for (int c = 0; c < 36; ++c) {
    int flat = c * 256 + tid;          // 144*64 = 9216
    int d = flat >> 6, hh = flat & 63;
    float v = (d <= 128) ? rel[((size_t)(512 * 1024 + 448 + d)) * 64 + hh] : 0.f;
    Tb[d][hh] = f2bf(v);
  }
  // ---- zero band ----
  for (int c = 0; c < 33; ++c) {
    int flat = c * 256 + tid;          // 64*132 = 8448
    ((float*)&Bd[0][0])[flat] = 0.f;
  }
  __syncthreads();

  // Q A-fragments for this wave's 16 rows (kept in regs for whole kernel)
  short8 aq[2];
#pragma unroll
  for (int kk = 0; kk < 2; ++kk)
    aq[kk] = *(const short8*)(&Qs[16 * w + li][kk * 32 + g * 8]);

  // ---- qrel[i][d] = Q[i,:]·table[d,:]  (MFMA, 9 n-tiles cover 144 cols) ----
  {
    f32x4 qa[9];
#pragma unroll
    for (int nt = 0; nt < 9; ++nt) qa[nt] = (f32x4){0.f, 0.f, 0.f, 0.f};
#pragma unroll
    for (int kk = 0; kk < 2; ++kk)
#pragma unroll
      for (int nt = 0; nt < 9; ++nt) {
        short8 bt = *(const short8*)(&Tb[nt * 16 + li][kk * 32 + g * 8]);
        qa[nt] = __builtin_amdgcn_mfma_f32_16x16x32_bf16(aq[kk], bt, qa[nt], 0, 0, 0);
      }
#pragma unroll
    for (int nt = 0; nt < 9; ++nt) {
      int d = nt * 16 + li;
      if (d <= 128) {
#pragma unroll
        for (int r = 0; r < 4; ++r)
          Qr[16 * w + g * 4 + r][d] = f2bf(qa[nt][r]);
      }
    }
  }

  f32x4 cacc[4];
#pragma unroll
  for (int nt = 0; nt < 4; ++nt) cacc[nt] = (f32x4){0.f, 0.f, 0.f, 0.f};
  float tsum[4] = {0.f, 0.f, 0.f, 0.f};
  float lsum[4] = {0.f, 0.f, 0.f, 0.f};
  float rsum[4] = {0.f, 0.f, 0.f, 0.f};

  const size_t kvbase = ((size_t)(b * SEQ)) * 1024 + h * HDIM;

  for (int t = 0; t < 8; ++t) {
    int j0 = t * 128;
    __syncthreads();   // previous PV done before overwriting K/Vt
    // stage K [128][64]
#pragma unroll
    for (int c = 0; c < 4; ++c) {
      int flat = c * 256 + tid;
      int row = flat >> 3, col = (flat & 7) * 8;
      *(uint4*)(&u.a.Ks[row][col]) = *(const uint4*)(Kb + kvbase + (size_t)(j0 + row) * 1024 + col);
    }
    // stage V transposed: Vt[h][j]
#pragma unroll
    for (int c = 0; c < 4; ++c) {
      int flat = c * 256 + tid;
      int row = flat >> 3, col = (flat & 7) * 8;
      uint4 v = *(const uint4*)(Vb + kvbase + (size_t)(j0 + row) * 1024 + col);
      const u16* pv = (const u16*)&v;
#pragma unroll
      for (int e = 0; e < 8; ++e) u.a.Vt[col + e][row] = pv[e];
    }
    __syncthreads();

    // ---- QK^T: 16x128 per wave ----
    f32x4 sa[8];
#pragma unroll
    for (int nt = 0; nt < 8; ++nt) sa[nt] = (f32x4){0.f, 0.f, 0.f, 0.f};
#pragma unroll
    for (int kk = 0; kk < 2; ++kk)
#pragma unroll
      for (int nt = 0; nt < 8; ++nt) {
        short8 bk = *(const short8*)(&u.a.Ks[nt * 16 + li][kk * 32 + g * 8]);
        sa[nt] = __builtin_amdgcn_mfma_f32_16x16x32_bf16(aq[kk], bk, sa[nt], 0, 0, 0);
      }

    // ---- bias + exp + band/rowsum bookkeeping + P to LDS ----
#pragma unroll
    for (int nt = 0; nt < 8; ++nt) {
      int jl = nt * 16 + li;
      int jg = j0 + jl;
#pragma unroll
      for (int r = 0; r < 4; ++r) {
        int il = 16 * w + g * 4 + r;
        int ig = i0 + il;
        int dist = jg - ig;
        int d = dist < -64 ? 0 : (dist > 64 ? 128 : dist + 64);
        // p = exp((qk + qrel)/8) = exp2((qk+qrel) * 0.125*log2(e))
        float p = exp2f((sa[nt][r] + bf2f(Qr[il][d])) * 0.18033688011112042f);
        u.a.Ps[il][jl] = f2bf(p);
        tsum[r] += p;
        if (dist <= -64)      lsum[r] += p;           // all map to bucket 0
        else if (dist >= 64)  rsum[r] += p;           // all map to bucket 128
        else                  Bd[il][dist + 64] = p;  // unique (i,d) globally -> plain store
      }
    }
    __syncthreads();

    // ---- PV: ctx += P · V ----
#pragma unroll
    for (int kt = 0; kt < 4; ++kt) {
      short8 pa = *(const short8*)(&u.a.Ps[16 * w + li][kt * 32 + g * 8]);
#pragma unroll
      for (int nt = 0; nt < 4; ++nt) {
        short8 bv = *(const short8*)(&u.a.Vt[nt * 16 + li][kt * 32 + g * 8]);
        cacc[nt] = __builtin_amdgcn_mfma_f32_16x16x32_bf16(pa, bv, cacc[nt], 0, 0, 0);
      }
    }
  }
  __syncthreads();

  // ---- reduce row sums across the 16 lanes sharing a row ----
#pragma unroll
  for (int r = 0; r < 4; ++r) {
#pragma unroll
    for (int m = 1; m < 16; m <<= 1) {
      tsum[r] += __shfl_xor(tsum[r], m, 16);
      lsum[r] += __shfl_xor(lsum[r], m, 16);
      rsum[r] += __shfl_xor(rsum[r], m, 16);
    }
  }
  if (li == 0) {
#pragma unroll
    for (int r = 0; r < 4; ++r) {
      Bd[16 * w + g * 4 + r][0]   = lsum[r];
      Bd[16 * w + g * 4 + r][128] = rsum[r];
    }
  }
  __syncthreads();

  // ---- build bf16 band (cols padded to 160 with zeros) and transposed table ----
  for (int c = 0; c < 40; ++c) {
    int flat = c * 256 + tid;          // 64*160 = 10240
    int row = flat / 160, col = flat % 160;
    u.e.Bb[row][col] = (col <= 128) ? f2bf(Bd[row][col]) : (u16)0;
    u.e.Tt[row][col] = (col <= 128) ? Tb[col][row] : (u16)0;   // Tt[h][d] = table[d][h]
  }
  __syncthreads();

  // ---- rel-value term: ctx += band · table  (K = 160 padded) ----
#pragma unroll
  for (int kt = 0; kt < 5; ++kt) {
    short8 pa = *(const short8*)(&u.e.Bb[16 * w + li][kt * 32 + g * 8]);
#pragma unroll
    for (int nt = 0; nt < 4; ++nt) {
      short8 bv = *(const short8*)(&u.e.Tt[nt * 16 + li][kt * 32 + g * 8]);
      cacc[nt] = __builtin_amdgcn_mfma_f32_16x16x32_bf16(pa, bv, cacc[nt], 0, 0, 0);
    }
  }

  // ---- normalize and store ctx (bf16) ----
  const size_t obase = ((size_t)(b * SEQ + i0)) * 1024 + h * HDIM;
#pragma unroll
  for (int r = 0; r < 4; ++r) {
    float inv = 1.f / tsum[r];
    int il = 16 * w + g * 4 + r;
#pragma unroll
    for (int nt = 0; nt < 4; ++nt)
      Cb[obase + (size_t)il * 1024 + nt * 16 + li] = f2bf(cacc[nt][r] * inv);
  }
}

// ---------------- launch ----------------
extern "C" void kernel_launch(void* const* d_in, const int* in_sizes, int n_in,
                              void* d_out, int out_size, void* d_ws, size_t ws_size,
                              hipStream_t stream) {
  const float* H   = (const float*)d_in[0];
  const float* Wq  = (const float*)d_in[1];
  const float* bq  = (const float*)d_in[2];
  const float* Wk  = (const float*)d_in[3];
  const float* bk  = (const float*)d_in[4];
  const float* Wv  = (const float*)d_in[5];
  const float* bv  = (const float*)d_in[6];
  const float* Wo  = (const float*)d_in[7];
  const float* bo  = (const float*)d_in[8];
  const float* rel = (const float*)d_in[9];
  float* out = (float*)d_out;

  // workspace layout (requires ~88 MB)
  char* ws = (char*)d_ws;
  u16* Hb  = (u16*)(ws);
  u16* Wqb = (u16*)(ws + 16777216);
  u16* Wkb = (u16*)(ws + 18874368);
  u16* Wvb = (u16*)(ws + 20971520);
  u16* Wob = (u16*)(ws + 23068672);
  u16* Qb  = (u16*)(ws + 25165824);
  u16* Kb  = (u16*)(ws + 41943040);
  u16* Vb  = (u16*)(ws + 58720256);
  u16* Cb  = (u16*)(ws + 75497472);

  cvt_f32_bf16<<<8192, 256, 0, stream>>>(H,  Hb,  8388608);
  cvt_f32_bf16<<<1024, 256, 0, stream>>>(Wq, Wqb, 1048576);
  cvt_f32_bf16<<<1024, 256, 0, stream>>>(Wk, Wkb, 1048576);
  cvt_f32_bf16<<<1024, 256, 0, stream>>>(Wv, Wvb, 1048576);
  cvt_f32_bf16<<<1024, 256, 0, stream>>>(Wo, Wob, 1048576);

  dim3 gg(8, 64);   // N/128, M/128
  gemm_bt<0><<<gg, 256, 0, stream>>>(Hb, Wqb, bq, Qb, 8192, 1024, 1024);
  gemm_bt<0><<<gg, 256, 0, stream>>>(Hb, Wkb, bk, Kb, 8192, 1024, 1024);
  gemm_bt<0><<<gg, 256, 0, stream>>>(Hb, Wvb, bv, Vb, 8192, 1024, 1024);

  attn_kernel<<<2048, 256, 0, stream>>>(Qb, Kb, Vb, rel, Cb);

  gemm_bt<1><<<gg, 256, 0, stream>>>(Cb, Wob, bo, out, 8192, 1024, 1024);
}

// Round 2
// 664.499 us; speedup vs baseline: 1.5846x; 1.5846x over previous
//
#include <hip/hip_runtime.h>
#include <hip/hip_bf16.h>
#include <stdint.h>

// Problem constants (fixed benchmark): B=8, S=1024, HID=1024, NH=16, HD=64, MAX_REL=64
#define SEQ 1024

typedef unsigned short u16;
typedef __attribute__((ext_vector_type(8))) short short8;
typedef __attribute__((ext_vector_type(4))) float f32x4;

static __device__ __forceinline__ u16 f2bf(float f) {
  union { float f; unsigned int u; } v; v.f = f;
  unsigned int u = v.u;
  unsigned int r = u + 0x7fffu + ((u >> 16) & 1u);   // RNE
  return (u16)(r >> 16);
}
static __device__ __forceinline__ float bf2f(u16 h) {
  union { unsigned int u; float f; } v; v.u = ((unsigned int)h) << 16;
  return v.f;
}

// ---- direct-to-LDS 16B async copy (m97 lever). LDS dest must be wave-uniform;
// HW adds lane*16. Cast through uintptr_t (CK-style) for address spaces. ----
typedef __attribute__((address_space(3))) uint32_t lds_u32;
typedef const __attribute__((address_space(1))) uint32_t glb_u32;
static __device__ __forceinline__ void gload_lds16(const void* g, void* l) {
  __builtin_amdgcn_global_load_lds((glb_u32*)(uintptr_t)g, (lds_u32*)(uintptr_t)l, 16, 0, 0);
}

// ---------------- f32 -> bf16 convert ----------------
__global__ __launch_bounds__(256) void cvt_f32_bf16(const float* __restrict__ src,
                                                    u16* __restrict__ dst, int n) {
  int i = (blockIdx.x * 256 + threadIdx.x) * 4;
  if (i < n) {
    float4 v = *(const float4*)(src + i);
    ushort4 o;
    o.x = f2bf(v.x); o.y = f2bf(v.y); o.z = f2bf(v.z); o.w = f2bf(v.w);
    *(ushort4*)(dst + i) = o;
  }
}

// ---------------- GEMM: C = A @ Bw^T + bias (m97 structure) ----------------
// A [M][K] bf16, Bw [N][K] bf16. 128x128 tile, BK=32, 256 threads.
// global_load_lds width=16 into LINEAR LDS, double-buffer, 1 barrier/K-step.
template<int OUTF32>
__global__ __launch_bounds__(256) void gemm_bt(const u16* __restrict__ A,
                                               const u16* __restrict__ Bw,
                                               const float* __restrict__ bias,
                                               void* __restrict__ Cout,
                                               int M, int N, int K) {
  const int tid  = threadIdx.x;
  const int lane = tid & 63;
  const int w    = tid >> 6;
  const int g    = lane >> 4;
  const int li   = lane & 15;
  const int m0 = blockIdx.y * 128;
  const int n0 = blockIdx.x * 128;
  const int wm = (w >> 1) * 64;
  const int wn = (w & 1) * 64;

  __shared__ alignas(16) u16 As[2][128 * 32];   // linear: required by global_load_lds
  __shared__ alignas(16) u16 Bs[2][128 * 32];

  f32x4 acc[4][4];
#pragma unroll
  for (int mt = 0; mt < 4; ++mt)
#pragma unroll
    for (int nt = 0; nt < 4; ++nt) acc[mt][nt] = (f32x4){0.f, 0.f, 0.f, 0.f};

  const int KT = K >> 5;

  auto issue = [&](int t, int bb) {
#pragma unroll
    for (int c = 0; c < 2; ++c) {
      int u   = c * 256 + tid;          // 16B chunk id; row = u>>2, col = (u&3)*8
      int row = u >> 2, col = (u & 3) * 8;
      const u16* ga = A  + (size_t)(m0 + row) * K + t * 32 + col;
      const u16* gb = Bw + (size_t)(n0 + row) * K + t * 32 + col;
      // wave-uniform LDS base; HW adds lane*16
      u16* la = &As[bb][(c * 256 + w * 64) * 8];
      u16* lb = &Bs[bb][(c * 256 + w * 64) * 8];
      gload_lds16(ga, la);
      gload_lds16(gb, lb);
    }
  };

  issue(0, 0);
  for (int t = 0; t < KT; ++t) {
    __syncthreads();                      // drains vmcnt -> buf[t&1] ready
    if (t + 1 < KT) issue(t + 1, (t + 1) & 1);
    const u16* as = As[t & 1];
    const u16* bs = Bs[t & 1];
    short8 af[4], bfr[4];
#pragma unroll
    for (int mt = 0; mt < 4; ++mt)
      af[mt] = *(const short8*)(&as[(wm + mt * 16 + li) * 32 + g * 8]);
#pragma unroll
    for (int nt = 0; nt < 4; ++nt)
      bfr[nt] = *(const short8*)(&bs[(wn + nt * 16 + li) * 32 + g * 8]);
#pragma unroll
    for (int mt = 0; mt < 4; ++mt)
#pragma unroll
      for (int nt = 0; nt < 4; ++nt)
        acc[mt][nt] = __builtin_amdgcn_mfma_f32_16x16x32_bf16(af[mt], bfr[nt], acc[mt][nt], 0, 0, 0);
  }

#pragma unroll
  for (int mt = 0; mt < 4; ++mt) {
#pragma unroll
    for (int nt = 0; nt < 4; ++nt) {
      int col = n0 + wn + nt * 16 + li;
      float bv = bias[col];
#pragma unroll
      for (int r = 0; r < 4; ++r) {
        int row = m0 + wm + mt * 16 + g * 4 + r;
        float v = acc[mt][nt][r] + bv;
        if (OUTF32) ((float*)Cout)[(size_t)row * N + col] = v;
        else        ((u16*)Cout)[(size_t)row * N + col]   = f2bf(v);
      }
    }
  }
}

// ---------------- V transpose: Vb[(b*S+j)][h*64+hd] -> Vt[(bh*64+hd)][j] ----------------
// One block per (bh, 128-j tile). XOR-swizzled LDS (16B-chunk granularity) so both the
// coalesced store and the column-gather read are ~conflict-free.
__global__ __launch_bounds__(256) void transpose_v(const u16* __restrict__ Vb,
                                                   u16* __restrict__ Vt) {
  const int tid = threadIdx.x;
  const int bh = blockIdx.x >> 3;
  const int jt = blockIdx.x & 7;
  const int b  = bh >> 4, h = bh & 15;
  const int j0 = jt * 128;
  __shared__ alignas(16) u16 Ls[128][64];

#pragma unroll
  for (int c = 0; c < 4; ++c) {
    int flat = c * 256 + tid;              // 1024 chunks of 8 u16 over [128 j][64 hd]
    int j = flat >> 3, hd8 = flat & 7;
    int ch = hd8 ^ ((j >> 3) & 7);         // swizzle 16B chunks within row by j>>3
    *(uint4*)(&Ls[j][ch * 8]) =
        *(const uint4*)(Vb + (size_t)(b * SEQ + j0 + j) * 1024 + h * 64 + hd8 * 8);
  }
  __syncthreads();
#pragma unroll
  for (int c = 0; c < 4; ++c) {
    int flat = c * 256 + tid;              // 1024 chunks of 8 over [64 hd][128 j]
    int hd = flat >> 4, jj = (flat & 15) * 8;
    int cx = ((hd >> 3) ^ ((jj >> 3) & 7)) * 8 + (hd & 7);
    u16 tmp[8];
#pragma unroll
    for (int e = 0; e < 8; ++e) tmp[e] = Ls[jj + e][cx];
    *(uint4*)(Vt + (size_t)(bh * 64 + hd) * SEQ + j0 + jj) = *(uint4*)tmp;
  }
}

// ---------------- Fused attention with rank-129 relative embedding ----------------
// rel[i,j,:] = table[clip(j-i,-64,64)+64,:]; table rebuilt per block from rel row 512.
// Block: one (b,h), 64 q-rows, 4 waves (wave w owns rows 16w..16w+15). j-tile = 64.
// LDS ~63.5KB -> 2 blocks/CU.
__global__ __launch_bounds__(256) void attn_kernel(const u16* __restrict__ Qb,
                                                   const u16* __restrict__ Kb,
                                                   const u16* __restrict__ Vt,
                                                   const float* __restrict__ rel,
                                                   u16* __restrict__ Cb) {
  const int tid  = threadIdx.x;
  const int lane = tid & 63;
  const int w    = tid >> 6;
  const int g    = lane >> 4;
  const int li   = lane & 15;

  const int bh = blockIdx.x >> 4;   // b*16+h
  const int it = blockIdx.x & 15;
  const int b  = bh >> 4;
  const int h  = bh & 15;
  const int i0 = it * 64;

  union SU {
    struct { u16 Ks[64][72]; u16 Vs[64][72]; u16 Ps[64][72]; } m;  // main loop (27648B)
    struct { u16 Tn[144][72]; } i;                                 // init: table (20736B)
    struct { u16 Tt[64][160]; } e;                                 // epilogue (20480B)
  };
  __shared__ alignas(16) SU su;
  __shared__ alignas(16) u16 Qr[64][132];   // qrel[i][d] bf16 (16896B)
  __shared__ alignas(16) u16 Bd[64][160];   // band[i][d] bf16, cols >=129 stay 0 (20480B)

  // ---- init: stage table Tn[d][hh], zero band ----
#pragma unroll
  for (int c = 0; c < 36; ++c) {
    int flat = c * 256 + tid;               // 144*64
    int d = flat >> 6, hh = flat & 63;
    float v = (d <= 128) ? rel[((size_t)(512 * 1024 + 448 + d)) * 64 + hh] : 0.f;
    su.i.Tn[d][hh] = f2bf(v);
  }
#pragma unroll
  for (int c = 0; c < 20; ++c)
    ((uint32_t*)Bd)[c * 256 + tid] = 0u;    // 5120 u32

  // ---- Q fragments straight from global (one-time, L2) ----
  const size_t qrow = ((size_t)(b * SEQ + i0 + 16 * w + li)) * 1024 + h * 64;
  short8 aq[2];
  aq[0] = *(const short8*)(Qb + qrow + g * 8);
  aq[1] = *(const short8*)(Qb + qrow + 32 + g * 8);
  __syncthreads();

  // ---- qrel[i][d] = Q[i,:]·table[d,:] ----
  {
    f32x4 qa[9];
#pragma unroll
    for (int nt = 0; nt < 9; ++nt) qa[nt] = (f32x4){0.f, 0.f, 0.f, 0.f};
#pragma unroll
    for (int kk = 0; kk < 2; ++kk)
#pragma unroll
      for (int nt = 0; nt < 9; ++nt) {
        short8 bt = *(const short8*)(&su.i.Tn[nt * 16 + li][kk * 32 + g * 8]);
        qa[nt] = __builtin_amdgcn_mfma_f32_16x16x32_bf16(aq[kk], bt, qa[nt], 0, 0, 0);
      }
#pragma unroll
    for (int nt = 0; nt < 9; ++nt) {
      int d = nt * 16 + li;
      if (d <= 128) {
#pragma unroll
        for (int r = 0; r < 4; ++r)
          Qr[16 * w + g * 4 + r][d] = f2bf(qa[nt][r]);
      }
    }
  }
  __syncthreads();   // Tn reads done (stage will overwrite), Qr visible

  f32x4 cacc[4];
#pragma unroll
  for (int nt = 0; nt < 4; ++nt) cacc[nt] = (f32x4){0.f, 0.f, 0.f, 0.f};
  float tsum[4] = {0.f, 0.f, 0.f, 0.f};
  float lsum[4] = {0.f, 0.f, 0.f, 0.f};
  float rsum[4] = {0.f, 0.f, 0.f, 0.f};

  const size_t kbase = ((size_t)(b * SEQ)) * 1024 + h * 64;
  const size_t vbase = ((size_t)bh) * 64 * SEQ;

  for (int t = 0; t < 16; ++t) {
    const int j0 = t * 64;
    // stage K [64 j][64 hd] and V^T [64 hd][64 j], both coalesced uint4
#pragma unroll
    for (int c = 0; c < 2; ++c) {
      int uu = c * 256 + tid;               // 512 chunks of 8
      int row = uu >> 3, col = (uu & 7) * 8;
      *(uint4*)(&su.m.Ks[row][col]) =
          *(const uint4*)(Kb + kbase + (size_t)(j0 + row) * 1024 + col);
      *(uint4*)(&su.m.Vs[row][col]) =
          *(const uint4*)(Vt + vbase + (size_t)row * SEQ + j0 + col);
    }
    __syncthreads();

    // ---- QK^T: 16x64 per wave ----
    f32x4 sa[4];
#pragma unroll
    for (int nt = 0; nt < 4; ++nt) sa[nt] = (f32x4){0.f, 0.f, 0.f, 0.f};
#pragma unroll
    for (int kk = 0; kk < 2; ++kk)
#pragma unroll
      for (int nt = 0; nt < 4; ++nt) {
        short8 bk = *(const short8*)(&su.m.Ks[nt * 16 + li][kk * 32 + g * 8]);
        sa[nt] = __builtin_amdgcn_mfma_f32_16x16x32_bf16(aq[kk], bk, sa[nt], 0, 0, 0);
      }

    // ---- bias + exp + band/rowsum + P to LDS ----
#pragma unroll
    for (int nt = 0; nt < 4; ++nt) {
      int jl = nt * 16 + li;
      int jg = j0 + jl;
#pragma unroll
      for (int r = 0; r < 4; ++r) {
        int il = 16 * w + g * 4 + r;
        int ig = i0 + il;
        int dist = jg - ig;
        int d = dist < -64 ? 0 : (dist > 64 ? 128 : dist + 64);
        float p = exp2f((sa[nt][r] + bf2f(Qr[il][d])) * 0.18033688011112042f);
        su.m.Ps[il][jl] = f2bf(p);
        tsum[r] += p;
        if (dist <= -64)      lsum[r] += p;
        else if (dist >= 64)  rsum[r] += p;
        else                  Bd[il][dist + 64] = f2bf(p);  // unique (i,d) globally
      }
    }
    __syncthreads();

    // ---- PV: ctx += P · V ----
#pragma unroll
    for (int kt = 0; kt < 2; ++kt) {
      short8 pa = *(const short8*)(&su.m.Ps[16 * w + li][kt * 32 + g * 8]);
#pragma unroll
      for (int nt = 0; nt < 4; ++nt) {
        short8 bv = *(const short8*)(&su.m.Vs[nt * 16 + li][kt * 32 + g * 8]);
        cacc[nt] = __builtin_amdgcn_mfma_f32_16x16x32_bf16(pa, bv, cacc[nt], 0, 0, 0);
      }
    }
    __syncthreads();   // PV reads done before next stage overwrites
  }

  // ---- reduce row sums across the 16 lanes sharing a row ----
#pragma unroll
  for (int r = 0; r < 4; ++r) {
#pragma unroll
    for (int m = 1; m < 16; m <<= 1) {
      tsum[r] += __shfl_xor(tsum[r], m, 16);
      lsum[r] += __shfl_xor(lsum[r], m, 16);
      rsum[r] += __shfl_xor(rsum[r], m, 16);
    }
  }
  if (li == 0) {
#pragma unroll
    for (int r = 0; r < 4; ++r) {
      Bd[16 * w + g * 4 + r][0]   = f2bf(lsum[r]);
      Bd[16 * w + g * 4 + r][128] = f2bf(rsum[r]);
    }
  }
  // ---- stage transposed table Tt[hh][d] (coalesced rel reads, 2B LDS scatter) ----
#pragma unroll
  for (int c = 0; c < 40; ++c) {
    int flat = c * 256 + tid;               // [160 d][64 hh]
    int d = flat >> 6, hh = flat & 63;
    float v = (d <= 128) ? rel[((size_t)(512 * 1024 + 448 + d)) * 64 + hh] : 0.f;
    su.e.Tt[hh][d] = f2bf(v);
  }
  __syncthreads();

  // ---- rel-value term: ctx += band · table (K = 160, cols>=129 zero) ----
#pragma unroll
  for (int kt = 0; kt < 5; ++kt) {
    short8 pa = *(const short8*)(&Bd[16 * w + li][kt * 32 + g * 8]);
#pragma unroll
    for (int nt = 0; nt < 4; ++nt) {
      short8 bv = *(const short8*)(&su.e.Tt[nt * 16 + li][kt * 32 + g * 8]);
      cacc[nt] = __builtin_amdgcn_mfma_f32_16x16x32_bf16(pa, bv, cacc[nt], 0, 0, 0);
    }
  }

  // ---- normalize and store ctx (bf16) ----
  const size_t obase = ((size_t)(b * SEQ + i0)) * 1024 + h * 64;
#pragma unroll
  for (int r = 0; r < 4; ++r) {
    float inv = 1.f / tsum[r];
    int il = 16 * w + g * 4 + r;
#pragma unroll
    for (int nt = 0; nt < 4; ++nt)
      Cb[obase + (size_t)il * 1024 + nt * 16 + li] = f2bf(cacc[nt][r] * inv);
  }
}

// ---------------- launch ----------------
extern "C" void kernel_launch(void* const* d_in, const int* in_sizes, int n_in,
                              void* d_out, int out_size, void* d_ws, size_t ws_size,
                              hipStream_t stream) {
  const float* H   = (const float*)d_in[0];
  const float* Wq  = (const float*)d_in[1];
  const float* bq  = (const float*)d_in[2];
  const float* Wk  = (const float*)d_in[3];
  const float* bk  = (const float*)d_in[4];
  const float* Wv  = (const float*)d_in[5];
  const float* bv  = (const float*)d_in[6];
  const float* Wo  = (const float*)d_in[7];
  const float* bo  = (const float*)d_in[8];
  const float* rel = (const float*)d_in[9];
  float* out = (float*)d_out;

  // workspace layout (~88 MB, same footprint as round 1)
  char* ws = (char*)d_ws;
  u16* Hb  = (u16*)(ws);                    // 16MB; dead after V-gemm, reused for Vt
  u16* Wqb = (u16*)(ws + 16777216);
  u16* Wkb = (u16*)(ws + 18874368);
  u16* Wvb = (u16*)(ws + 20971520);
  u16* Wob = (u16*)(ws + 23068672);
  u16* Qb  = (u16*)(ws + 25165824);
  u16* Kb  = (u16*)(ws + 41943040);
  u16* Vb  = (u16*)(ws + 58720256);
  u16* Cb  = (u16*)(ws + 75497472);
  u16* Vtb = Hb;                            // V transposed [bh*64+hd][S]

  cvt_f32_bf16<<<8192, 256, 0, stream>>>(H,  Hb,  8388608);
  cvt_f32_bf16<<<1024, 256, 0, stream>>>(Wq, Wqb, 1048576);
  cvt_f32_bf16<<<1024, 256, 0, stream>>>(Wk, Wkb, 1048576);
  cvt_f32_bf16<<<1024, 256, 0, stream>>>(Wv, Wvb, 1048576);
  cvt_f32_bf16<<<1024, 256, 0, stream>>>(Wo, Wob, 1048576);

  dim3 gg(8, 64);   // N/128, M/128
  gemm_bt<0><<<gg, 256, 0, stream>>>(Hb, Wqb, bq, Qb, 8192, 1024, 1024);
  gemm_bt<0><<<gg, 256, 0, stream>>>(Hb, Wkb, bk, Kb, 8192, 1024, 1024);
  gemm_bt<0><<<gg, 256, 0, stream>>>(Hb, Wvb, bv, Vb, 8192, 1024, 1024);

  transpose_v<<<1024, 256, 0, stream>>>(Vb, Vtb);

  attn_kernel<<<2048, 256, 0, stream>>>(Qb, Kb, Vtb, rel, Cb);

  gemm_bt<1><<<gg, 256, 0, stream>>>(Cb, Wob, bo, out, 8192, 1024, 1024);
}

// Round 4
// 650.442 us; speedup vs baseline: 1.6189x; 1.0216x over previous
//
#include <hip/hip_runtime.h>
#include <hip/hip_bf16.h>
#include <stdint.h>

// Problem constants (fixed benchmark): B=8, S=1024, HID=1024, NH=16, HD=64, MAX_REL=64
#define SEQ 1024

typedef unsigned short u16;
typedef __attribute__((ext_vector_type(8))) short short8;
typedef __attribute__((ext_vector_type(4))) float f32x4;

static __device__ __forceinline__ u16 f2bf(float f) {
  union { float f; unsigned int u; } v; v.f = f;
  unsigned int u = v.u;
  unsigned int r = u + 0x7fffu + ((u >> 16) & 1u);   // RNE
  return (u16)(r >> 16);
}
static __device__ __forceinline__ float bf2f(u16 h) {
  union { unsigned int u; float f; } v; v.u = ((unsigned int)h) << 16;
  return v.f;
}

// ---- direct-to-LDS 16B async copy. LDS dest wave-uniform; HW adds lane*16. ----
typedef __attribute__((address_space(3))) uint32_t lds_u32;
typedef const __attribute__((address_space(1))) uint32_t glb_u32;
static __device__ __forceinline__ void gload_lds16(const void* g, void* l) {
  __builtin_amdgcn_global_load_lds((glb_u32*)(uintptr_t)g, (lds_u32*)(uintptr_t)l, 16, 0, 0);
}

// ---------------- f32 -> bf16 convert ----------------
__global__ __launch_bounds__(256) void cvt_f32_bf16(const float* __restrict__ src,
                                                    u16* __restrict__ dst, int n) {
  int i = (blockIdx.x * 256 + threadIdx.x) * 4;
  if (i < n) {
    float4 v = *(const float4*)(src + i);
    ushort4 o;
    o.x = f2bf(v.x); o.y = f2bf(v.y); o.z = f2bf(v.z); o.w = f2bf(v.w);
    *(ushort4*)(dst + i) = o;
  }
}

// ---------------- Out-proj GEMM: C = A @ Bw^T + bias, f32 out (m97 structure) ----------------
__global__ __launch_bounds__(256) void gemm_out(const u16* __restrict__ A,
                                                const u16* __restrict__ Bw,
                                                const float* __restrict__ bias,
                                                float* __restrict__ Cout,
                                                int M, int N, int K) {
  const int tid  = threadIdx.x;
  const int lane = tid & 63;
  const int w    = tid >> 6;
  const int g    = lane >> 4;
  const int li   = lane & 15;
  const int m0 = blockIdx.y * 128;
  const int n0 = blockIdx.x * 128;
  const int wm = (w >> 1) * 64;
  const int wn = (w & 1) * 64;

  __shared__ alignas(16) u16 As[2][128 * 32];
  __shared__ alignas(16) u16 Bs[2][128 * 32];

  f32x4 acc[4][4];
#pragma unroll
  for (int mt = 0; mt < 4; ++mt)
#pragma unroll
    for (int nt = 0; nt < 4; ++nt) acc[mt][nt] = (f32x4){0.f, 0.f, 0.f, 0.f};

  const int KT = K >> 5;

  auto issue = [&](int t, int bb) {
#pragma unroll
    for (int c = 0; c < 2; ++c) {
      int u   = c * 256 + tid;
      int row = u >> 2, col = (u & 3) * 8;
      const u16* ga = A  + (size_t)(m0 + row) * K + t * 32 + col;
      const u16* gb = Bw + (size_t)(n0 + row) * K + t * 32 + col;
      u16* la = &As[bb][(c * 256 + w * 64) * 8];
      u16* lb = &Bs[bb][(c * 256 + w * 64) * 8];
      gload_lds16(ga, la);
      gload_lds16(gb, lb);
    }
  };

  issue(0, 0);
  for (int t = 0; t < KT; ++t) {
    __syncthreads();
    if (t + 1 < KT) issue(t + 1, (t + 1) & 1);
    const u16* as = As[t & 1];
    const u16* bs = Bs[t & 1];
    short8 af[4], bfr[4];
#pragma unroll
    for (int mt = 0; mt < 4; ++mt)
      af[mt] = *(const short8*)(&as[(wm + mt * 16 + li) * 32 + g * 8]);
#pragma unroll
    for (int nt = 0; nt < 4; ++nt)
      bfr[nt] = *(const short8*)(&bs[(wn + nt * 16 + li) * 32 + g * 8]);
#pragma unroll
    for (int mt = 0; mt < 4; ++mt)
#pragma unroll
      for (int nt = 0; nt < 4; ++nt)
        acc[mt][nt] = __builtin_amdgcn_mfma_f32_16x16x32_bf16(af[mt], bfr[nt], acc[mt][nt], 0, 0, 0);
  }

#pragma unroll
  for (int mt = 0; mt < 4; ++mt) {
#pragma unroll
    for (int nt = 0; nt < 4; ++nt) {
      int col = n0 + wn + nt * 16 + li;
      float bv = bias[col];
#pragma unroll
      for (int r = 0; r < 4; ++r) {
        int row = m0 + wm + mt * 16 + g * 4 + r;
        Cout[(size_t)row * N + col] = acc[mt][nt][r] + bv;
      }
    }
  }
}

// ---------------- Fused QKV GEMM: [8192 x 3072] = H @ Wcat^T ----------------
// Q,K written [token][1024]; V written transposed: Vt[(b*16+h)*64+hd][s].
__global__ __launch_bounds__(256) void gemm_qkv(const u16* __restrict__ A,
                                                const u16* __restrict__ Wc,
                                                const float* __restrict__ bq,
                                                const float* __restrict__ bk,
                                                const float* __restrict__ bv,
                                                u16* __restrict__ Qb,
                                                u16* __restrict__ Kb,
                                                u16* __restrict__ Vtb) {
  const int tid  = threadIdx.x;
  const int lane = tid & 63;
  const int w    = tid >> 6;
  const int g    = lane >> 4;
  const int li   = lane & 15;
  const int m0 = blockIdx.y * 128;
  const int n0 = blockIdx.x * 128;
  const int wm = (w >> 1) * 64;
  const int wn = (w & 1) * 64;
  const int K = 1024;

  __shared__ alignas(16) u16 As[2][128 * 32];
  __shared__ alignas(16) u16 Bs[2][128 * 32];

  f32x4 acc[4][4];
#pragma unroll
  for (int mt = 0; mt < 4; ++mt)
#pragma unroll
    for (int nt = 0; nt < 4; ++nt) acc[mt][nt] = (f32x4){0.f, 0.f, 0.f, 0.f};

  auto issue = [&](int t, int bb) {
#pragma unroll
    for (int c = 0; c < 2; ++c) {
      int u   = c * 256 + tid;
      int row = u >> 2, col = (u & 3) * 8;
      const u16* ga = A  + (size_t)(m0 + row) * K + t * 32 + col;
      const u16* gb = Wc + (size_t)(n0 + row) * K + t * 32 + col;
      u16* la = &As[bb][(c * 256 + w * 64) * 8];
      u16* lb = &Bs[bb][(c * 256 + w * 64) * 8];
      gload_lds16(ga, la);
      gload_lds16(gb, lb);
    }
  };

  issue(0, 0);
  for (int t = 0; t < 32; ++t) {
    __syncthreads();
    if (t + 1 < 32) issue(t + 1, (t + 1) & 1);
    const u16* as = As[t & 1];
    const u16* bs = Bs[t & 1];
    short8 af[4], bfr[4];
#pragma unroll
    for (int mt = 0; mt < 4; ++mt)
      af[mt] = *(const short8*)(&as[(wm + mt * 16 + li) * 32 + g * 8]);
#pragma unroll
    for (int nt = 0; nt < 4; ++nt)
      bfr[nt] = *(const short8*)(&bs[(wn + nt * 16 + li) * 32 + g * 8]);
#pragma unroll
    for (int mt = 0; mt < 4; ++mt)
#pragma unroll
      for (int nt = 0; nt < 4; ++nt)
        acc[mt][nt] = __builtin_amdgcn_mfma_f32_16x16x32_bf16(af[mt], bfr[nt], acc[mt][nt], 0, 0, 0);
  }

  const int mat = n0 >> 10;          // 0=Q, 1=K, 2=V (uniform per block)
  if (mat < 2) {
    u16* dst = mat ? Kb : Qb;
    const float* bp = mat ? bk : bq;
    const int cb = n0 & 1023;
#pragma unroll
    for (int mt = 0; mt < 4; ++mt) {
#pragma unroll
      for (int nt = 0; nt < 4; ++nt) {
        int col = cb + wn + nt * 16 + li;
        float bvv = bp[col];
#pragma unroll
        for (int r = 0; r < 4; ++r) {
          int row = m0 + wm + mt * 16 + g * 4 + r;
          dst[(size_t)row * 1024 + col] = f2bf(acc[mt][nt][r] + bvv);
        }
      }
    }
  } else {
    // V: write transposed. token m -> (batch=m>>10, s=m&1023); ncol = h*64+hd
#pragma unroll
    for (int mt = 0; mt < 4; ++mt) {
#pragma unroll
      for (int nt = 0; nt < 4; ++nt) {
        int ncol = (n0 & 1023) + wn + nt * 16 + li;
        float bvv = bv[ncol];
        int mbase = m0 + wm + mt * 16 + g * 4;      // 4 consecutive tokens, same batch
        size_t vrow = ((size_t)((mbase >> 10) * 16 + (ncol >> 6))) * 64 + (ncol & 63);
        ushort4 pk;
        pk.x = f2bf(acc[mt][nt][0] + bvv);
        pk.y = f2bf(acc[mt][nt][1] + bvv);
        pk.z = f2bf(acc[mt][nt][2] + bvv);
        pk.w = f2bf(acc[mt][nt][3] + bvv);
        *(ushort4*)(Vtb + vrow * 1024 + (mbase & 1023)) = pk;
      }
    }
  }
}

// ---------------- Fused attention (round-2 verified version, verbatim) ----------------
// rel[i,j,:] = table[clip(j-i,-64,64)+64,:]. Block: one (b,h), 64 q-rows, 4 waves.
// j-tile = 64. LDS ~63.5KB -> 2 blocks/CU.
__global__ __launch_bounds__(256) void attn_kernel(const u16* __restrict__ Qb,
                                                   const u16* __restrict__ Kb,
                                                   const u16* __restrict__ Vt,
                                                   const float* __restrict__ rel,
                                                   u16* __restrict__ Cb) {
  const int tid  = threadIdx.x;
  const int lane = tid & 63;
  const int w    = tid >> 6;
  const int g    = lane >> 4;
  const int li   = lane & 15;

  const int bh = blockIdx.x >> 4;   // b*16+h
  const int it = blockIdx.x & 15;
  const int b  = bh >> 4;
  const int h  = bh & 15;
  const int i0 = it * 64;

  union SU {
    struct { u16 Ks[64][72]; u16 Vs[64][72]; u16 Ps[64][72]; } m;  // main loop (27648B)
    struct { u16 Tn[144][72]; } i;                                 // init: table (20736B)
    struct { u16 Tt[64][160]; } e;                                 // epilogue (20480B)
  };
  __shared__ alignas(16) SU su;
  __shared__ alignas(16) u16 Qr[64][132];   // qrel[i][d] bf16 (16896B)
  __shared__ alignas(16) u16 Bd[64][160];   // band[i][d] bf16, cols >=129 stay 0 (20480B)

  // ---- init: stage table Tn[d][hh], zero band ----
#pragma unroll
  for (int c = 0; c < 36; ++c) {
    int flat = c * 256 + tid;               // 144*64
    int d = flat >> 6, hh = flat & 63;
    float v = (d <= 128) ? rel[((size_t)(512 * 1024 + 448 + d)) * 64 + hh] : 0.f;
    su.i.Tn[d][hh] = f2bf(v);
  }
#pragma unroll
  for (int c = 0; c < 20; ++c)
    ((uint32_t*)Bd)[c * 256 + tid] = 0u;    // 5120 u32

  // ---- Q fragments straight from global (one-time, L2) ----
  const size_t qrow = ((size_t)(b * SEQ + i0 + 16 * w + li)) * 1024 + h * 64;
  short8 aq[2];
  aq[0] = *(const short8*)(Qb + qrow + g * 8);
  aq[1] = *(const short8*)(Qb + qrow + 32 + g * 8);
  __syncthreads();   // Tn visible

  // ---- qrel[i][d] = Q[i,:]·table[d,:] ----
  {
    f32x4 qa[9];
#pragma unroll
    for (int nt = 0; nt < 9; ++nt) qa[nt] = (f32x4){0.f, 0.f, 0.f, 0.f};
#pragma unroll
    for (int kk = 0; kk < 2; ++kk)
#pragma unroll
      for (int nt = 0; nt < 9; ++nt) {
        short8 bt = *(const short8*)(&su.i.Tn[nt * 16 + li][kk * 32 + g * 8]);
        qa[nt] = __builtin_amdgcn_mfma_f32_16x16x32_bf16(aq[kk], bt, qa[nt], 0, 0, 0);
      }
#pragma unroll
    for (int nt = 0; nt < 9; ++nt) {
      int d = nt * 16 + li;
      if (d <= 128) {
#pragma unroll
        for (int r = 0; r < 4; ++r)
          Qr[16 * w + g * 4 + r][d] = f2bf(qa[nt][r]);   // wave-local rows
      }
    }
  }
  __syncthreads();   // all Tn reads done; su.m may be written

  f32x4 cacc[4];
#pragma unroll
  for (int nt = 0; nt < 4; ++nt) cacc[nt] = (f32x4){0.f, 0.f, 0.f, 0.f};
  float tsum[4] = {0.f, 0.f, 0.f, 0.f};
  float lsum[4] = {0.f, 0.f, 0.f, 0.f};
  float rsum[4] = {0.f, 0.f, 0.f, 0.f};

  const size_t kbase = ((size_t)(b * SEQ)) * 1024 + h * 64;
  const size_t vbase = ((size_t)bh) * 64 * 1024;

  for (int t = 0; t < 16; ++t) {
    const int j0 = t * 64;
    // stage K [64 j][64 hd] and V^T [64 hd][64 j], both coalesced uint4
#pragma unroll
    for (int c = 0; c < 2; ++c) {
      int uu = c * 256 + tid;               // 512 chunks of 8
      int row = uu >> 3, col = (uu & 7) * 8;
      *(uint4*)(&su.m.Ks[row][col]) =
          *(const uint4*)(Kb + kbase + (size_t)(j0 + row) * 1024 + col);
      *(uint4*)(&su.m.Vs[row][col]) =
          *(const uint4*)(Vt + vbase + (size_t)row * SEQ + j0 + col);
    }
    __syncthreads();

    // ---- QK^T: 16x64 per wave ----
    f32x4 sa[4];
#pragma unroll
    for (int nt = 0; nt < 4; ++nt) sa[nt] = (f32x4){0.f, 0.f, 0.f, 0.f};
#pragma unroll
    for (int kk = 0; kk < 2; ++kk)
#pragma unroll
      for (int nt = 0; nt < 4; ++nt) {
        short8 bk = *(const short8*)(&su.m.Ks[nt * 16 + li][kk * 32 + g * 8]);
        sa[nt] = __builtin_amdgcn_mfma_f32_16x16x32_bf16(aq[kk], bk, sa[nt], 0, 0, 0);
      }

    // ---- bias + exp + band/rowsum + P to LDS ----
#pragma unroll
    for (int nt = 0; nt < 4; ++nt) {
      int jl = nt * 16 + li;
      int jg = j0 + jl;
#pragma unroll
      for (int r = 0; r < 4; ++r) {
        int il = 16 * w + g * 4 + r;
        int ig = i0 + il;
        int dist = jg - ig;
        int d = dist < -64 ? 0 : (dist > 64 ? 128 : dist + 64);
        float p = exp2f((sa[nt][r] + bf2f(Qr[il][d])) * 0.18033688011112042f);
        su.m.Ps[il][jl] = f2bf(p);
        tsum[r] += p;
        if (dist <= -64)      lsum[r] += p;
        else if (dist >= 64)  rsum[r] += p;
        else                  Bd[il][dist + 64] = f2bf(p);  // unique (i,d) globally
      }
    }
    __syncthreads();

    // ---- PV: ctx += P · V ----
#pragma unroll
    for (int kt = 0; kt < 2; ++kt) {
      short8 pa = *(const short8*)(&su.m.Ps[16 * w + li][kt * 32 + g * 8]);
#pragma unroll
      for (int nt = 0; nt < 4; ++nt) {
        short8 bvv = *(const short8*)(&su.m.Vs[nt * 16 + li][kt * 32 + g * 8]);
        cacc[nt] = __builtin_amdgcn_mfma_f32_16x16x32_bf16(pa, bvv, cacc[nt], 0, 0, 0);
      }
    }
    __syncthreads();   // all K/V/P reads done before next stage write
  }

  // ---- stage transposed table Tt[hh][d] over su.m ----
#pragma unroll
  for (int c = 0; c < 40; ++c) {
    int flat = c * 256 + tid;               // [160 d][64 hh]
    int d = flat >> 6, hh = flat & 63;
    float v = (d <= 128) ? rel[((size_t)(512 * 1024 + 448 + d)) * 64 + hh] : 0.f;
    su.e.Tt[hh][d] = f2bf(v);
  }

  // ---- reduce row sums across the 16 lanes sharing a row ----
#pragma unroll
  for (int r = 0; r < 4; ++r) {
#pragma unroll
    for (int m = 1; m < 16; m <<= 1) {
      tsum[r] += __shfl_xor(tsum[r], m, 16);
      lsum[r] += __shfl_xor(lsum[r], m, 16);
      rsum[r] += __shfl_xor(rsum[r], m, 16);
    }
  }
  if (li == 0) {
#pragma unroll
    for (int r = 0; r < 4; ++r) {
      int il = 16 * w + g * 4 + r;
      Bd[il][0]   = f2bf(lsum[r]);
      Bd[il][128] = f2bf(rsum[r]);
    }
  }
  __syncthreads();   // Tt ready (cross-wave)

  // ---- rel-value term: ctx += band · table (K=160, cols>128 zero) ----
#pragma unroll
  for (int kt = 0; kt < 5; ++kt) {
    short8 pa = *(const short8*)(&Bd[16 * w + li][kt * 32 + g * 8]);
#pragma unroll
    for (int nt = 0; nt < 4; ++nt) {
      short8 bvv = *(const short8*)(&su.e.Tt[nt * 16 + li][kt * 32 + g * 8]);
      cacc[nt] = __builtin_amdgcn_mfma_f32_16x16x32_bf16(pa, bvv, cacc[nt], 0, 0, 0);
    }
  }

  // ---- normalize and store ctx (bf16) ----
  const size_t obase = ((size_t)(b * SEQ + i0)) * 1024 + h * 64;
#pragma unroll
  for (int r = 0; r < 4; ++r) {
    float inv = 1.f / tsum[r];
    int il = 16 * w + g * 4 + r;
#pragma unroll
    for (int nt = 0; nt < 4; ++nt)
      Cb[obase + (size_t)il * 1024 + nt * 16 + li] = f2bf(cacc[nt][r] * inv);
  }
}

// ---------------- launch ----------------
extern "C" void kernel_launch(void* const* d_in, const int* in_sizes, int n_in,
                              void* d_out, int out_size, void* d_ws, size_t ws_size,
                              hipStream_t stream) {
  const float* H   = (const float*)d_in[0];
  const float* Wq  = (const float*)d_in[1];
  const float* bq  = (const float*)d_in[2];
  const float* Wk  = (const float*)d_in[3];
  const float* bk  = (const float*)d_in[4];
  const float* Wv  = (const float*)d_in[5];
  const float* bv  = (const float*)d_in[6];
  const float* Wo  = (const float*)d_in[7];
  const float* bo  = (const float*)d_in[8];
  const float* rel = (const float*)d_in[9];
  float* out = (float*)d_out;

  // workspace layout (~88 MB)
  char* ws = (char*)d_ws;
  u16* Hb   = (u16*)(ws);                       // 16 MB
  u16* Wcat = (u16*)(ws + 16777216);            //  6 MB  [3072][1024] bf16
  u16* Wob  = (u16*)(ws + 23068672);            //  2 MB
  u16* Qb   = (u16*)(ws + 25165824);            // 16 MB
  u16* Kb   = (u16*)(ws + 41943040);            // 16 MB
  u16* Vtb  = (u16*)(ws + 58720256);            // 16 MB  [(b*16+h)*64+hd][1024]
  u16* Cb   = (u16*)(ws + 75497472);            // 16 MB

  cvt_f32_bf16<<<8192, 256, 0, stream>>>(H,  Hb,  8388608);
  cvt_f32_bf16<<<1024, 256, 0, stream>>>(Wq, Wcat,           1048576);
  cvt_f32_bf16<<<1024, 256, 0, stream>>>(Wk, Wcat + 1048576, 1048576);
  cvt_f32_bf16<<<1024, 256, 0, stream>>>(Wv, Wcat + 2097152, 1048576);
  cvt_f32_bf16<<<1024, 256, 0, stream>>>(Wo, Wob, 1048576);

  gemm_qkv<<<dim3(24, 64), 256, 0, stream>>>(Hb, Wcat, bq, bk, bv, Qb, Kb, Vtb);

  attn_kernel<<<2048, 256, 0, stream>>>(Qb, Kb, Vtb, rel, Cb);

  gemm_out<<<dim3(8, 64), 256, 0, stream>>>(Cb, Wob, bo, out, 8192, 1024, 1024);
}